// Round 9
// baseline (382.656 us; speedup 1.0000x reference)
//
#include <hip/hip_runtime.h>
#include <math.h>

// Fused CBAM spatial mask, v3 (VALU-bound fix: vertical register reuse):
//   thread = 4 output rows x 4 cols (16 outputs); wave = 64 lanes = full 256-col
//   row-quad. block = 256 thr = 4 waves = 16 rows; grid = (16, B*T) = 2048 blocks.
// Unified rolling pooled-row buffers (pm=max, ps=sum) shared by both conv paths:
// 8 input rows -> 6 pooled rows -> 4 output rows, all in registers. No masked
// weight prep (raw cw scalars); edge gating = wave-uniform scalar branches only.

#define H 256
#define W 256
#define NEG_INF (-__builtin_inff())

__device__ __forceinline__ float uniform_f(float v) {
    // force wave-uniform float into an SGPR
    return __int_as_float(__builtin_amdgcn_readfirstlane(__float_as_int(v)));
}

__global__ __launch_bounds__(256, 4)
void cbam_fused_kernel(const float* __restrict__ x,
                       const float* __restrict__ cw,
                       const float* __restrict__ cb,
                       float* __restrict__ out)
{
    const int tid  = threadIdx.x;
    const int lane = tid & 63;                  // cols lane*4 .. lane*4+3
    const int wq   = tid >> 6;                  // row-quad within block
    const int rb   = blockIdx.x * 16 + wq * 4;  // first output row (wave-uniform)
    const int bt   = blockIdx.y;
    const int c0   = lane * 4;

    const bool lane0  = (lane == 0);
    const bool lane63 = (lane == 63);
    const bool top = (rb == 0);       // input rows rb-2,rb-1 & pooled rb-1 invalid
    const bool bot = (rb == H - 4);   // input rows rb+4,rb+5 & pooled rb+4 invalid

    float acc[4][4];
    #pragma unroll
    for (int o = 0; o < 4; ++o)
        #pragma unroll
        for (int j = 0; j < 4; ++j) acc[o][j] = 0.f;

    #pragma unroll 1
    for (int c = 0; c < 3; ++c) {
        const float* ch = x + (size_t)(bt * 3 + c) * (H * W);

        // raw conv weights, wave-uniform -> SGPR. avg plane pre-scaled by 1/9
        // (AvgPool count_include_pad divides by 9 everywhere).
        float wm[9], wa[9];
        #pragma unroll
        for (int k = 0; k < 9; ++k) {
            wm[k] = uniform_f(cw[(2 * c) * 9 + k]);
            wa[k] = uniform_f(cw[(2 * c + 1) * 9 + k] * (1.f / 9.f));
        }

        // rolling pooled-row buffers; pooled rel row pr (abs p = rb-1+pr) in slot pr%3.
        // Step i: reset slot pr=i (i<=5); input row gr=rb-2+i feeds pr in {i-2,i-1,i};
        // pooled row pr=i-2 completes after step i -> conv-apply. Aliasing verified:
        // every slot applied (step pr+2) before its reset reuse (step pr+3).
        float pm[3][6], ps[3][6];

        #pragma unroll
        for (int i = 0; i < 8; ++i) {
            if (i <= 5) {
                const int q = i % 3;
                #pragma unroll
                for (int j = 0; j < 6; ++j) { pm[q][j] = NEG_INF; ps[q][j] = 0.f; }
            }

            const int gr = rb - 2 + i;
            // rows rb..rb+3 (i=2..5) are always in-bounds: compile-time true.
            const bool rowvalid = (i >= 2 && i <= 5) ? true : (i < 2 ? !top : !bot);
            if (rowvalid) {
                const float* rp = ch + (size_t)gr * W;
                // aligned 12-float slab [c0-4, c0+8); edge lanes clamp addr, mask vals
                const float4 L = *(const float4*)(rp + (lane0  ? 0  : c0 - 4));
                const float4 M = *(const float4*)(rp + c0);
                const float4 R = *(const float4*)(rp + (lane63 ? c0 : c0 + 4));

                const float z2 = lane0  ? 0.f : L.z;      // col c0-2 (sum id 0)
                const float z3 = lane0  ? 0.f : L.w;      // col c0-1
                const float z8 = lane63 ? 0.f : R.x;      // col c0+4
                const float z9 = lane63 ? 0.f : R.y;      // col c0+5
                const float m2 = lane0  ? NEG_INF : L.z;  // max identity -inf
                const float m3 = lane0  ? NEG_INF : L.w;
                const float m8 = lane63 ? NEG_INF : R.x;
                const float m9 = lane63 ? NEG_INF : R.y;

                // 6 column windows j (pooled cols c0-1+j)
                float rm[6], rs[6];
                rm[0] = fmaxf(fmaxf(m2,  m3),  M.x);  rs[0] = z2 + z3 + M.x;
                rm[1] = fmaxf(fmaxf(m3,  M.x), M.y);  rs[1] = z3 + M.x + M.y;
                rm[2] = fmaxf(fmaxf(M.x, M.y), M.z);  rs[2] = M.x + M.y + M.z;
                rm[3] = fmaxf(fmaxf(M.y, M.z), M.w);  rs[3] = M.y + M.z + M.w;
                rm[4] = fmaxf(fmaxf(M.z, M.w), m8);   rs[4] = M.z + M.w + z8;
                rm[5] = fmaxf(fmaxf(M.w, m8),  m9);   rs[5] = M.w + z8 + z9;
                // pooled cols -1 / 256 are conv zero-pad -> sums stay 0 there
                rs[0] = lane0  ? 0.f : rs[0];
                rs[5] = lane63 ? 0.f : rs[5];

                #pragma unroll
                for (int d = -2; d <= 0; ++d) {
                    const int pr = i + d;                 // pooled rows fed by gr
                    if (pr < 0 || pr > 5) continue;       // compile-time clamp
                    const int q = pr % 3;
                    #pragma unroll
                    for (int j = 0; j < 6; ++j) {
                        pm[q][j] = fmaxf(pm[q][j], rm[j]);
                        ps[q][j] += rs[j];
                    }
                }
            }

            // conv-apply completed pooled row pr = i-2 (abs p = rb-1+pr)
            if (i >= 2) {
                const int pr = i - 2;
                const int q = pr % 3;
                const bool pvalid = (pr >= 1 && pr <= 4) ? true
                                                         : (pr == 0 ? !top : !bot);
                if (pvalid) {
                    // pooled cols -1/256 are conv zero-pad for the max plane
                    const float P0 = lane0  ? 0.f : pm[q][0];
                    const float P5 = lane63 ? 0.f : pm[q][5];
                    const float P1 = pm[q][1], P2 = pm[q][2],
                                P3 = pm[q][3], P4 = pm[q][4];
                    #pragma unroll
                    for (int orel = pr - 2; orel <= pr; ++orel) {
                        if (orel < 0 || orel > 3) continue;   // compile-time
                        const int kr = pr - orel;             // conv kh, 0..2
                        const float km0 = wm[kr*3+0], km1 = wm[kr*3+1], km2 = wm[kr*3+2];
                        const float ka0 = wa[kr*3+0], ka1 = wa[kr*3+1], ka2 = wa[kr*3+2];
                        acc[orel][0] = fmaf(km0,P0, fmaf(km1,P1, fmaf(km2,P2, acc[orel][0])));
                        acc[orel][1] = fmaf(km0,P1, fmaf(km1,P2, fmaf(km2,P3, acc[orel][1])));
                        acc[orel][2] = fmaf(km0,P2, fmaf(km1,P3, fmaf(km2,P4, acc[orel][2])));
                        acc[orel][3] = fmaf(km0,P3, fmaf(km1,P4, fmaf(km2,P5, acc[orel][3])));
                        acc[orel][0] = fmaf(ka0,ps[q][0], fmaf(ka1,ps[q][1], fmaf(ka2,ps[q][2], acc[orel][0])));
                        acc[orel][1] = fmaf(ka0,ps[q][1], fmaf(ka1,ps[q][2], fmaf(ka2,ps[q][3], acc[orel][1])));
                        acc[orel][2] = fmaf(ka0,ps[q][2], fmaf(ka1,ps[q][3], fmaf(ka2,ps[q][4], acc[orel][2])));
                        acc[orel][3] = fmaf(ka0,ps[q][3], fmaf(ka1,ps[q][4], fmaf(ka2,ps[q][5], acc[orel][3])));
                    }
                }
            }
        }
    }

    // epilogue: bias -> LeakyReLU -> sigmoid -> broadcast to 3 channels
    const float bias = uniform_f(cb[0]);
    float* ob = out + (size_t)(bt * 3) * (H * W) + (size_t)rb * W + c0;
    #pragma unroll
    for (int o = 0; o < 4; ++o) {
        float4 res;
        float* rp = (float*)&res;
        #pragma unroll
        for (int j = 0; j < 4; ++j) {
            float y = acc[o][j] + bias;
            y = (y >= 0.f) ? y : 0.01f * y;
            rp[j] = 1.f / (1.f + expf(-y));
        }
        float* obr = ob + (size_t)o * W;
        *(float4*)(obr)              = res;   // wave: 1KB contiguous per plane
        *(float4*)(obr + H * W)      = res;
        *(float4*)(obr + 2 * H * W)  = res;
    }
}

extern "C" void kernel_launch(void* const* d_in, const int* in_sizes, int n_in,
                              void* d_out, int out_size, void* d_ws, size_t ws_size,
                              hipStream_t stream) {
    const float* x  = (const float*)d_in[0];
    const float* cw = (const float*)d_in[1];   // [1,6,3,3] = 54 floats
    const float* cb = (const float*)d_in[2];   // [1]
    float* out = (float*)d_out;

    const int BT_in  = in_sizes[0] / (3 * H * W);
    const int BT_out = out_size    / (3 * H * W);
    if (BT_in <= 0 || BT_in != BT_out ||
        in_sizes[0] != BT_in * 3 * H * W || out_size != BT_in * 3 * H * W ||
        n_in < 3 || in_sizes[1] < 54 || in_sizes[2] < 1)
        return;

    dim3 grid(H / 16, BT_in);       // 16 x 128 = 2048 blocks
    dim3 block(256);                // 4 waves; wave = 4 output rows x 256 cols
    cbam_fused_kernel<<<grid, block, 0, stream>>>(x, cw, cb, out);
}